// Round 24
// baseline (299.858 us; speedup 1.0000x reference)
//
#include <hip/hip_runtime.h>
#include <stdint.h>

// ---------------------------------------------------------------------------
// Differential attention, bf16 MFMA pipeline.
// B=2 T=2048 C=2048 H=8 HD=256 HALF=128
// cast_all(r16) + gemm_qk(r23) + gemm_v(r23) + attn v10 + P-swizzle + gemm_out(r14)
// ---------------------------------------------------------------------------

typedef __bf16 bf16;
typedef bf16 bf16x8 __attribute__((ext_vector_type(8)));
typedef bf16 bf16x4 __attribute__((ext_vector_type(4)));
typedef float f32x4 __attribute__((ext_vector_type(4)));

typedef void __attribute__((address_space(1)))* gas_t;
typedef void __attribute__((address_space(3)))* las_t;

__device__ __forceinline__ void gload16(const void* g, void* l) {
  __builtin_amdgcn_global_load_lds((gas_t)(uintptr_t)g, (las_t)(uint32_t)(uintptr_t)l, 16, 0, 0);
}

__device__ __forceinline__ f32x4 mfma16x16(bf16x8 a, bf16x8 b, f32x4 c) {
  return __builtin_amdgcn_mfma_f32_16x16x32_bf16(a, b, c, 0, 0, 0);
}

// ---------------- fused casts + lambda (r16-verified) ----------------
__global__ __launch_bounds__(256) void cast_all(const float* __restrict__ x,
                                                const float* __restrict__ wq, const float* __restrict__ wk,
                                                const float* __restrict__ wv, const float* __restrict__ wo,
                                                const float* __restrict__ lq1, const float* __restrict__ lk1,
                                                const float* __restrict__ lq2, const float* __restrict__ lk2,
                                                bf16* __restrict__ xb,
                                                bf16* __restrict__ wqb, bf16* __restrict__ wkb,
                                                bf16* __restrict__ wvb, bf16* __restrict__ wob,
                                                float* __restrict__ lam) {
  __shared__ float red[8];
  int tid = threadIdx.x;
  int i = blockIdx.x * 256 + tid;
  const float* in;
  bf16* out;
  int j;
  if (i < 2097152) {
    in = x; out = xb; j = i;
  } else {
    int k = i - 2097152;
    int w = k >> 20;
    j = k & 1048575;
    in = (w == 0) ? wq : (w == 1) ? wk : (w == 2) ? wv : wo;
    out = (w == 0) ? wqb : (w == 1) ? wkb : (w == 2) ? wvb : wob;
  }
  float4 v = ((const float4*)in)[j];
  bf16x4 o;
  o[0] = (bf16)v.x; o[1] = (bf16)v.y; o[2] = (bf16)v.z; o[3] = (bf16)v.w;
  ((bf16x4*)out)[j] = o;

  if (blockIdx.x == 0) {  // lambda
    float a = lq1[tid] * lk1[tid];
    float b = lq2[tid] * lk2[tid];
#pragma unroll
    for (int m = 32; m >= 1; m >>= 1) {
      a += __shfl_xor(a, m, 64);
      b += __shfl_xor(b, m, 64);
    }
    if ((tid & 63) == 0) { red[tid >> 6] = a; red[4 + (tid >> 6)] = b; }
    __syncthreads();
    if (tid == 0) {
      float s1 = red[0] + red[1] + red[2] + red[3];
      float s2 = red[4] + red[5] + red[6] + red[7];
      lam[0] = expf(s1) - expf(s2) + 0.8f;
    }
  }
}

// ---------------- Q+K GEMM (r23-verified, ~61us): r7 engine, 256 blk zero-tail ----------------
__global__ __launch_bounds__(512, 2) void gemm_qk(const bf16* __restrict__ A,
                                                  const bf16* __restrict__ Bq,
                                                  const bf16* __restrict__ Bk,
                                                  bf16* __restrict__ Cq, bf16* __restrict__ Ck) {
  __shared__ char lds[98304];  // 3 x (A 16KB + B 16KB)
  const int K = 2048, nt = 64;

  int p = blockIdx.x;                 // 256 blocks
  int lid = (p & 7) * 32 + (p >> 3);  // bijective XCD swizzle
  const int bm = (lid >> 4) * 256;
  const int bnG = (lid & 15) * 256;   // [0, 4096)
  const int z = bnG >> 11;            // 0: Q, 1: K
  const int bn = bnG & 2047;
  const bf16* B = (z == 0) ? Bq : Bk;

  const int tid = threadIdx.x;
  const int wid = tid >> 6, lane = tid & 63;
  const int l15 = lane & 15, lhi = lane >> 4;
  const int wm = wid >> 2, wn = wid & 3;

  const bf16* aS0 = A + (size_t)(bm + wid * 16 + l15) * K + lhi * 8;
  const bf16* bS0 = B + (size_t)(bn + wid * 16 + l15) * K + lhi * 8;

  auto stA = [&](int t, int pb) {
    char* d = lds + pb * 32768 + wid * 1024;
    const bf16* s = aS0 + t * 32;
    gload16(s, d);
    gload16(s + (size_t)128 * K, d + 8192);
  };
  auto stB = [&](int t, int pb) {
    char* d = lds + pb * 32768 + 16384 + wid * 1024;
    const bf16* s = bS0 + t * 32;
    gload16(s, d);
    gload16(s + (size_t)128 * K, d + 8192);
  };

  const f32x4 fz = {0.f, 0.f, 0.f, 0.f};
  f32x4 acc[8][4];
#pragma unroll
  for (int m = 0; m < 8; ++m)
#pragma unroll
    for (int n = 0; n < 4; ++n) acc[m][n] = fz;

  stA(0, 0); stB(0, 0);
  stA(1, 1); stB(1, 1);
  asm volatile("s_waitcnt vmcnt(4)" ::: "memory");
  __builtin_amdgcn_s_barrier();

  int cur = 0;
  for (int t = 0; t < nt; ++t) {
    const char* ab = lds + cur * 32768;
    const char* bb = ab + 16384;
    int nx2 = cur + 2; if (nx2 >= 3) nx2 -= 3;
    bf16x8 a[8], b0, b1;

#pragma unroll
    for (int m = 0; m < 8; ++m) a[m] = *(const bf16x8*)(ab + (wm * 8 + m) * 1024 + lane * 16);
    b0 = *(const bf16x8*)(bb + (wn * 4 + 0) * 1024 + lane * 16);
    b1 = *(const bf16x8*)(bb + (wn * 4 + 1) * 1024 + lane * 16);
    if (t + 2 < nt) stA(t + 2, nx2);
    __builtin_amdgcn_s_barrier();
    __builtin_amdgcn_s_setprio(1);
#pragma unroll
    for (int m = 0; m < 8; ++m) {
      acc[m][0] = mfma16x16(a[m], b0, acc[m][0]);
      acc[m][1] = mfma16x16(a[m], b1, acc[m][1]);
    }
    __builtin_amdgcn_s_setprio(0);
    __builtin_amdgcn_s_barrier();

    b0 = *(const bf16x8*)(bb + (wn * 4 + 2) * 1024 + lane * 16);
    b1 = *(const bf16x8*)(bb + (wn * 4 + 3) * 1024 + lane * 16);
    if (t + 2 < nt) stB(t + 2, nx2);
    __builtin_amdgcn_s_barrier();
    __builtin_amdgcn_s_setprio(1);
#pragma unroll
    for (int m = 0; m < 8; ++m) {
      acc[m][2] = mfma16x16(a[m], b0, acc[m][2]);
      acc[m][3] = mfma16x16(a[m], b1, acc[m][3]);
    }
    __builtin_amdgcn_s_setprio(0);
    if (t + 2 < nt) {
      asm volatile("s_waitcnt vmcnt(4)" ::: "memory");
    } else {
      asm volatile("s_waitcnt vmcnt(0)" ::: "memory");
    }
    __builtin_amdgcn_s_barrier();

    cur = (cur == 2) ? 0 : cur + 1;
  }

  // rms-norm epilogue (f32 accum)
  float* ldsf = (float*)lds;
#pragma unroll
  for (int m = 0; m < 8; ++m)
#pragma unroll
    for (int r = 0; r < 4; ++r) {
      float s = acc[m][0][r] * acc[m][0][r] + acc[m][1][r] * acc[m][1][r] +
                acc[m][2][r] * acc[m][2][r] + acc[m][3][r] * acc[m][3][r];
      s += __shfl_xor(s, 1, 64);
      s += __shfl_xor(s, 2, 64);
      s += __shfl_xor(s, 4, 64);
      s += __shfl_xor(s, 8, 64);
      if (l15 == 0) ldsf[(wm * 128 + m * 16 + lhi * 4 + r) * 4 + wn] = s;
    }
  __syncthreads();
  const float osc = (z == 0) ? 0.08838834764831845f : 1.0f;  // fold 1/sqrt(128) into q
  bf16* C = (z == 0) ? Cq : Ck;
#pragma unroll
  for (int m = 0; m < 8; ++m) {
#pragma unroll
    for (int r = 0; r < 4; ++r) {
      int rl = wm * 128 + m * 16 + lhi * 4 + r;
      float tot = ldsf[rl * 4 + (wn & 2)] + ldsf[rl * 4 + (wn & 2) + 1];
      float sc = rsqrtf(tot * (1.0f / 128.0f) + 1.1920929e-07f) * osc;
#pragma unroll
      for (int n = 0; n < 4; ++n) {
        int col = bn + wn * 64 + n * 16 + l15;
        C[(size_t)(bm + rl) * 2048 + col] = (bf16)(acc[m][n][r] * sc);
      }
    }
  }
}

// ---------------- V GEMM (r23-verified, ~46us): r14 engine + V-transpose epilogue ----------------
__global__ __launch_bounds__(512) void gemm_v(const bf16* __restrict__ A, const bf16* __restrict__ B,
                                              bf16* __restrict__ Cv) {
  __shared__ char lds[73728];  // 3 x (A 16KB + B 8KB)
  const int K = 2048, nt = 64;

  int p = blockIdx.x;
  int lid = (p & 7) * 32 + (p >> 3);
  const int bm = (lid >> 4) * 256;
  const int bn = (lid & 15) * 128;

  const int tid = threadIdx.x;
  const int wid = tid >> 6, lane = tid & 63;
  const int l15 = lane & 15, lhi = lane >> 4;
  const int wm = wid >> 1, wn = wid & 1;

  const bf16* aB = A + (size_t)(bm + wid * 16 + l15) * K + lhi * 8;
  const bf16* bB = B + (size_t)(bn + wid * 16 + l15) * K + lhi * 8;

  auto stage = [&](int t, int pb) {
    char* base = lds + pb * 24576;
    const int k0 = t * 32;
    gload16(aB + k0, base + wid * 1024);
    gload16(aB + (size_t)128 * K + k0, base + 8192 + wid * 1024);
    gload16(bB + k0, base + 16384 + wid * 1024);
  };

  const f32x4 fz = {0.f, 0.f, 0.f, 0.f};
  f32x4 acc[4][4];
#pragma unroll
  for (int m = 0; m < 4; ++m)
#pragma unroll
    for (int n = 0; n < 4; ++n) acc[m][n] = fz;

  stage(0, 0);
  stage(1, 1);
  asm volatile("s_waitcnt vmcnt(3)" ::: "memory");
  __builtin_amdgcn_s_barrier();

  for (int t = 0; t < nt; ++t) {
    const char* ab = lds + (t % 3) * 24576;
    if (t + 2 < nt) stage(t + 2, (t + 2) % 3);
    bf16x8 a[4], b[4];
#pragma unroll
    for (int m = 0; m < 4; ++m)
      a[m] = *(const bf16x8*)(ab + (wm * 4 + m) * 1024 + lane * 16);
#pragma unroll
    for (int n = 0; n < 4; ++n)
      b[n] = *(const bf16x8*)(ab + 16384 + (wn * 4 + n) * 1024 + lane * 16);
    __builtin_amdgcn_s_setprio(1);
#pragma unroll
    for (int m = 0; m < 4; ++m)
#pragma unroll
      for (int n = 0; n < 4; ++n) acc[m][n] = mfma16x16(a[m], b[n], acc[m][n]);
    __builtin_amdgcn_s_setprio(0);
    if (t + 2 < nt) {
      asm volatile("s_waitcnt vmcnt(3)" ::: "memory");
    } else {
      asm volatile("s_waitcnt vmcnt(0)" ::: "memory");
    }
    __builtin_amdgcn_s_barrier();
  }

  // V-transpose epilogue: write vtb[b][d][t]
#pragma unroll
  for (int m = 0; m < 4; ++m)
#pragma unroll
    for (int n = 0; n < 4; ++n)
#pragma unroll
      for (int r = 0; r < 4; ++r) {
        int row = bm + wm * 64 + m * 16 + lhi * 4 + r;
        int col = bn + wn * 64 + n * 16 + l15;
        int bb3 = row >> 11, tt = row & 2047;
        Cv[(size_t)bb3 * 2048 * 2048 + (size_t)col * 2048 + tt] = (bf16)acc[m][n][r];
      }
}

// ---------------- output GEMM (r14-verified, ~46us): 256x128, 8 waves, 3-buf vmcnt(3) ----------------
__global__ __launch_bounds__(512) void gemm_out(const bf16* __restrict__ A, const bf16* __restrict__ B,
                                                float* __restrict__ Cf) {
  __shared__ char lds[73728];  // 3 x (A 16KB + B 8KB)
  const int K = 2048, nt = 64;

  int p = blockIdx.x;
  int lid = (p & 7) * 32 + (p >> 3);
  const int bm = (lid >> 4) * 256;
  const int bn = (lid & 15) * 128;

  const int tid = threadIdx.x;
  const int wid = tid >> 6, lane = tid & 63;
  const int l15 = lane & 15, lhi = lane >> 4;
  const int wm = wid >> 1, wn = wid & 1;

  const bf16* aB = A + (size_t)(bm + wid * 16 + l15) * K + lhi * 8;
  const bf16* bB = B + (size_t)(bn + wid * 16 + l15) * K + lhi * 8;

  auto stage = [&](int t, int pb) {
    char* base = lds + pb * 24576;
    const int k0 = t * 32;
    gload16(aB + k0, base + wid * 1024);
    gload16(aB + (size_t)128 * K + k0, base + 8192 + wid * 1024);
    gload16(bB + k0, base + 16384 + wid * 1024);
  };

  const f32x4 fz = {0.f, 0.f, 0.f, 0.f};
  f32x4 acc[4][4];
#pragma unroll
  for (int m = 0; m < 4; ++m)
#pragma unroll
    for (int n = 0; n < 4; ++n) acc[m][n] = fz;

  stage(0, 0);
  stage(1, 1);
  asm volatile("s_waitcnt vmcnt(3)" ::: "memory");
  __builtin_amdgcn_s_barrier();

  for (int t = 0; t < nt; ++t) {
    const char* ab = lds + (t % 3) * 24576;
    if (t + 2 < nt) stage(t + 2, (t + 2) % 3);
    bf16x8 a[4], b[4];
#pragma unroll
    for (int m = 0; m < 4; ++m)
      a[m] = *(const bf16x8*)(ab + (wm * 4 + m) * 1024 + lane * 16);
#pragma unroll
    for (int n = 0; n < 4; ++n)
      b[n] = *(const bf16x8*)(ab + 16384 + (wn * 4 + n) * 1024 + lane * 16);
    __builtin_amdgcn_s_setprio(1);
#pragma unroll
    for (int m = 0; m < 4; ++m)
#pragma unroll
      for (int n = 0; n < 4; ++n) acc[m][n] = mfma16x16(a[m], b[n], acc[m][n]);
    __builtin_amdgcn_s_setprio(0);
    if (t + 2 < nt) {
      asm volatile("s_waitcnt vmcnt(3)" ::: "memory");
    } else {
      asm volatile("s_waitcnt vmcnt(0)" ::: "memory");
    }
    __builtin_amdgcn_s_barrier();
  }

#pragma unroll
  for (int m = 0; m < 4; ++m)
#pragma unroll
    for (int n = 0; n < 4; ++n)
#pragma unroll
      for (int r = 0; r < 4; ++r) {
        int row = bm + wm * 64 + m * 16 + lhi * 4 + r;
        int col = bn + wn * 64 + n * 16 + l15;
        Cf[(size_t)row * 2048 + col] = acc[m][n][r] * 0.2f;
      }
}

// ---------------- dual-stream causal flash attention v10 + P-swizzle ----------------
// 8 waves of (stream s=wid>>2, rowgroup rg=wid&3, 16 q-rows), 2 blocks/CU, 4 waves/SIMD.
// K/VT double-buffer, stage at top of iter, ONE barrier/tile, balanced qt pairing.
// NEW: P buffer XOR-swizzled byte ^= (row&12)<<2 (row-keyed, bijective within 64B row,
// 16B-aligned) -> scalar P writes drop 8-way -> 4-way bank conflict; PA b128 read
// pattern preserved (XOR permutes lhi chunks bijectively).
__global__ __launch_bounds__(512, 4) void attn_kernel(const bf16* __restrict__ qb, const bf16* __restrict__ kb,
                                                      const bf16* __restrict__ vtb, bf16* __restrict__ yb,
                                                      const float* __restrict__ lamp) {
  __shared__ char lds[73728];
  const int tid = threadIdx.x;
  const int wid = tid >> 6, lane = tid & 63;
  const int l15 = lane & 15, lhi = lane >> 4;
  char* pl = lds + 65536 + wid * 1024;
  const int s = wid >> 2;   // stream (0: y1, 1: y2)
  const int rg = wid & 3;   // row-group (16 rows)

  const int p = blockIdx.x;
  const int bh = p & 15;
  const int qt = (p < 256) ? (31 - (p >> 4)) : ((p - 256) >> 4);
  const int b = bh >> 3, h = bh & 7;
  const int wr0 = qt * 64 + rg * 16;
  const float lam = lamp[0];

  bf16x8 qf[4];
  {
    const bf16* qrow = qb + (size_t)(b * 2048 + wr0 + l15) * 2048 + h * 256 + s * 128 + lhi * 8;
#pragma unroll
    for (int c = 0; c < 4; ++c) qf[c] = *(const bf16x8*)(qrow + c * 32);
  }

  const f32x4 fz = {0.f, 0.f, 0.f, 0.f};
  f32x4 y[16];
#pragma unroll
  for (int f = 0; f < 16; ++f) y[f] = fz;
  float lsum[4] = {0.f, 0.f, 0.f, 0.f};

  const int nkt = 2 * qt + 2;
  const bf16* kbase = kb + (size_t)(b * 2048) * 2048 + h * 256;
  const bf16* vbase = vtb + (size_t)b * 2048 * 2048 + (size_t)(h * 256) * 2048;

  auto stage = [&](int kt2, int pp) {
    const int t0 = kt2 * 32;
#pragma unroll
    for (int c = 0; c < 2; ++c) {
      int cc = wid * 2 + c;
      int ss = cc >> 3, tg = (cc >> 2) & 1, kc = cc & 3;
      const bf16* sp = kbase + (size_t)(t0 + tg * 16 + l15) * 2048 + ss * 128 + kc * 32 + lhi * 8;
      gload16(sp, lds + pp * 16384 + ss * 8192 + tg * 4096 + kc * 1024);
    }
#pragma unroll
    for (int c = 0; c < 2; ++c) {
      int cc = wid * 2 + c;
      int i = cc >> 2, w4 = cc & 3;
      const bf16* vp = vbase + (size_t)(i * 64 + w4 * 16 + l15) * 2048 + t0 + lhi * 8;
      gload16(vp, lds + 32768 + pp * 16384 + cc * 1024);
    }
  };

  stage(0, 0);
  __syncthreads();

  for (int kt = 0; kt < nkt; ++kt) {
    const int cur = kt & 1;
    const int t0 = kt * 32;
    const bool active = (t0 <= wr0 + 15);
    if (kt + 1 < nkt) stage(kt + 1, cur ^ 1);
    if (active) {
      const char* kc = lds + cur * 16384 + s * 8192;
      const char* vc = lds + 32768 + cur * 16384;
      f32x4 sg[2];
      __builtin_amdgcn_s_setprio(1);
#pragma unroll
      for (int g = 0; g < 2; ++g) {
        f32x4 a = fz;
#pragma unroll
        for (int ks = 0; ks < 4; ++ks)
          a = mfma16x16(qf[ks], *(const bf16x8*)(kc + (g * 4096 + ks * 1024) + lane * 16), a);
        sg[g] = a;
      }
      __builtin_amdgcn_s_setprio(0);
      if (t0 + 31 > wr0) {
#pragma unroll
        for (int g = 0; g < 2; ++g) {
          int col = t0 + g * 16 + l15;
#pragma unroll
          for (int r = 0; r < 4; ++r) {
            int row = wr0 + lhi * 4 + r;
            if (col > row) sg[g][r] = -1e30f;
          }
        }
      }
      // fixed-max softmax: p = exp(s-12); P write XOR-swizzled (row = lhi*4+r,
      // X(row) = (row&12)<<2 = lhi<<4)
#pragma unroll
      for (int g = 0; g < 2; ++g)
#pragma unroll
        for (int r = 0; r < 4; ++r) {
          float pv = __expf(sg[g][r] - 12.0f);
          lsum[r] += pv;
          int off = ((lhi * 4 + r) * 32 + g * 16 + l15) * 2;
          *(bf16*)(pl + (off ^ (lhi << 4))) = (bf16)pv;
        }
      // PA read: row = l15, chunk lhi -> byte = l15*64 + (lhi*16 ^ ((l15&12)<<2))
      bf16x8 pa = *(const bf16x8*)(pl + l15 * 64 + ((lhi * 16) ^ ((l15 & 12) << 2)));
      __builtin_amdgcn_s_setprio(1);
#pragma unroll
      for (int f = 0; f < 16; ++f) {
        bf16x8 vf = *(const bf16x8*)(vc + (f * 64 + lane) * 16);
        y[f] = mfma16x16(pa, vf, y[f]);
      }
      __builtin_amdgcn_s_setprio(0);
    }
    __syncthreads();
  }

  float inv[4];
#pragma unroll
  for (int r = 0; r < 4; ++r) {
    float sv = lsum[r];
    sv += __shfl_xor(sv, 1, 64);
    sv += __shfl_xor(sv, 2, 64);
    sv += __shfl_xor(sv, 4, 64);
    sv += __shfl_xor(sv, 8, 64);
    inv[r] = (s == 0) ? (1.f / sv) : (lam / sv);
  }
  __syncthreads();
  float* yx = (float*)lds;  // [64 rows][256 cols] f32
  if (s == 0) {
#pragma unroll
    for (int f = 0; f < 16; ++f)
#pragma unroll
      for (int r = 0; r < 4; ++r) {
        int rl = rg * 16 + lhi * 4 + r;
        yx[rl * 256 + f * 16 + l15] = y[f][r] * inv[r];
      }
  }
  __syncthreads();
  if (s == 1) {
#pragma unroll
    for (int r = 0; r < 4; ++r) {
      int rl = rg * 16 + lhi * 4 + r;
      bf16* orow = yb + (size_t)(b * 2048 + qt * 64 + rl) * 2048 + h * 256 + l15;
#pragma unroll
      for (int f = 0; f < 16; ++f) {
        float v = yx[rl * 256 + f * 16 + l15] - y[f][r] * inv[r];
        orow[f * 16] = (bf16)v;
      }
    }
  }
}

// ---------------------------------------------------------------------------
extern "C" void kernel_launch(void* const* d_in, const int* in_sizes, int n_in,
                              void* d_out, int out_size, void* d_ws, size_t ws_size,
                              hipStream_t stream) {
  const float* x = (const float*)d_in[0];
  const float* wq = (const float*)d_in[1];
  const float* wk = (const float*)d_in[2];
  const float* wv = (const float*)d_in[3];
  const float* wo = (const float*)d_in[4];
  const float* lq1 = (const float*)d_in[5];
  const float* lk1 = (const float*)d_in[6];
  const float* lq2 = (const float*)d_in[7];
  const float* lk2 = (const float*)d_in[8];
  float* out = (float*)d_out;
  char* ws = (char*)d_ws;

  if (ws_size < 117440516) return;

  bf16* xb = (bf16*)(ws + 0);             // [4096][2048]
  bf16* wqb = (bf16*)(ws + 16777216);     // [2048][2048]
  bf16* wkb = (bf16*)(ws + 25165824);
  bf16* wvb = (bf16*)(ws + 33554432);
  bf16* wob = (bf16*)(ws + 41943040);
  bf16* qbuf = (bf16*)(ws + 50331648);    // [4096][2048]
  bf16* kbuf = (bf16*)(ws + 67108864);    // [4096][2048]
  bf16* vtb = (bf16*)(ws + 83886080);     // [2][2048 d][2048 t]
  bf16* ybuf = (bf16*)(ws + 100663296);   // [4096][2048]
  float* lam = (float*)(ws + 117440512);

  cast_all<<<24576, 256, 0, stream>>>(x, wq, wk, wv, wo, lq1, lk1, lq2, lk2,
                                      xb, wqb, wkb, wvb, wob, lam);

  gemm_qk<<<256, 512, 0, stream>>>(xb, wqb, wkb, qbuf, kbuf);
  gemm_v<<<256, 512, 0, stream>>>(xb, wvb, vtb);

  attn_kernel<<<512, 512, 0, stream>>>(qbuf, kbuf, vtb, ybuf, lam);

  gemm_out<<<256, 512, 0, stream>>>(ybuf, wob, out);
}

// Round 25
// 288.435 us; speedup vs baseline: 1.0396x; 1.0396x over previous
//
#include <hip/hip_runtime.h>
#include <stdint.h>

// ---------------------------------------------------------------------------
// Differential attention, bf16 MFMA pipeline.
// B=2 T=2048 C=2048 H=8 HD=256 HALF=128
// FINAL (r23-verified, 288.5us): cast_all + gemm_qk + gemm_v + attn v10 + gemm_out
// ---------------------------------------------------------------------------

typedef __bf16 bf16;
typedef bf16 bf16x8 __attribute__((ext_vector_type(8)));
typedef bf16 bf16x4 __attribute__((ext_vector_type(4)));
typedef float f32x4 __attribute__((ext_vector_type(4)));

typedef void __attribute__((address_space(1)))* gas_t;
typedef void __attribute__((address_space(3)))* las_t;

__device__ __forceinline__ void gload16(const void* g, void* l) {
  __builtin_amdgcn_global_load_lds((gas_t)(uintptr_t)g, (las_t)(uint32_t)(uintptr_t)l, 16, 0, 0);
}

__device__ __forceinline__ f32x4 mfma16x16(bf16x8 a, bf16x8 b, f32x4 c) {
  return __builtin_amdgcn_mfma_f32_16x16x32_bf16(a, b, c, 0, 0, 0);
}

// ---------------- fused casts + lambda (r16-verified) ----------------
__global__ __launch_bounds__(256) void cast_all(const float* __restrict__ x,
                                                const float* __restrict__ wq, const float* __restrict__ wk,
                                                const float* __restrict__ wv, const float* __restrict__ wo,
                                                const float* __restrict__ lq1, const float* __restrict__ lk1,
                                                const float* __restrict__ lq2, const float* __restrict__ lk2,
                                                bf16* __restrict__ xb,
                                                bf16* __restrict__ wqb, bf16* __restrict__ wkb,
                                                bf16* __restrict__ wvb, bf16* __restrict__ wob,
                                                float* __restrict__ lam) {
  __shared__ float red[8];
  int tid = threadIdx.x;
  int i = blockIdx.x * 256 + tid;
  const float* in;
  bf16* out;
  int j;
  if (i < 2097152) {
    in = x; out = xb; j = i;
  } else {
    int k = i - 2097152;
    int w = k >> 20;
    j = k & 1048575;
    in = (w == 0) ? wq : (w == 1) ? wk : (w == 2) ? wv : wo;
    out = (w == 0) ? wqb : (w == 1) ? wkb : (w == 2) ? wvb : wob;
  }
  float4 v = ((const float4*)in)[j];
  bf16x4 o;
  o[0] = (bf16)v.x; o[1] = (bf16)v.y; o[2] = (bf16)v.z; o[3] = (bf16)v.w;
  ((bf16x4*)out)[j] = o;

  if (blockIdx.x == 0) {  // lambda
    float a = lq1[tid] * lk1[tid];
    float b = lq2[tid] * lk2[tid];
#pragma unroll
    for (int m = 32; m >= 1; m >>= 1) {
      a += __shfl_xor(a, m, 64);
      b += __shfl_xor(b, m, 64);
    }
    if ((tid & 63) == 0) { red[tid >> 6] = a; red[4 + (tid >> 6)] = b; }
    __syncthreads();
    if (tid == 0) {
      float s1 = red[0] + red[1] + red[2] + red[3];
      float s2 = red[4] + red[5] + red[6] + red[7];
      lam[0] = expf(s1) - expf(s2) + 0.8f;
    }
  }
}

// ---------------- Q+K GEMM (r23-verified, ~61us): r7 engine, 256 blk zero-tail ----------------
// 256x256 tile, 8 waves (2Mx4N), BK=32, 3 LDS buffers x 32KB, 2-phase rhythm,
// counted vmcnt(4). Split from V so the grid is exactly one balanced round.
__global__ __launch_bounds__(512, 2) void gemm_qk(const bf16* __restrict__ A,
                                                  const bf16* __restrict__ Bq,
                                                  const bf16* __restrict__ Bk,
                                                  bf16* __restrict__ Cq, bf16* __restrict__ Ck) {
  __shared__ char lds[98304];  // 3 x (A 16KB + B 16KB)
  const int K = 2048, nt = 64;

  int p = blockIdx.x;                 // 256 blocks
  int lid = (p & 7) * 32 + (p >> 3);  // bijective XCD swizzle
  const int bm = (lid >> 4) * 256;
  const int bnG = (lid & 15) * 256;   // [0, 4096)
  const int z = bnG >> 11;            // 0: Q, 1: K
  const int bn = bnG & 2047;
  const bf16* B = (z == 0) ? Bq : Bk;

  const int tid = threadIdx.x;
  const int wid = tid >> 6, lane = tid & 63;
  const int l15 = lane & 15, lhi = lane >> 4;
  const int wm = wid >> 2, wn = wid & 3;

  const bf16* aS0 = A + (size_t)(bm + wid * 16 + l15) * K + lhi * 8;
  const bf16* bS0 = B + (size_t)(bn + wid * 16 + l15) * K + lhi * 8;

  auto stA = [&](int t, int pb) {
    char* d = lds + pb * 32768 + wid * 1024;
    const bf16* s = aS0 + t * 32;
    gload16(s, d);
    gload16(s + (size_t)128 * K, d + 8192);
  };
  auto stB = [&](int t, int pb) {
    char* d = lds + pb * 32768 + 16384 + wid * 1024;
    const bf16* s = bS0 + t * 32;
    gload16(s, d);
    gload16(s + (size_t)128 * K, d + 8192);
  };

  const f32x4 fz = {0.f, 0.f, 0.f, 0.f};
  f32x4 acc[8][4];
#pragma unroll
  for (int m = 0; m < 8; ++m)
#pragma unroll
    for (int n = 0; n < 4; ++n) acc[m][n] = fz;

  stA(0, 0); stB(0, 0);
  stA(1, 1); stB(1, 1);
  asm volatile("s_waitcnt vmcnt(4)" ::: "memory");
  __builtin_amdgcn_s_barrier();

  int cur = 0;
  for (int t = 0; t < nt; ++t) {
    const char* ab = lds + cur * 32768;
    const char* bb = ab + 16384;
    int nx2 = cur + 2; if (nx2 >= 3) nx2 -= 3;
    bf16x8 a[8], b0, b1;

#pragma unroll
    for (int m = 0; m < 8; ++m) a[m] = *(const bf16x8*)(ab + (wm * 8 + m) * 1024 + lane * 16);
    b0 = *(const bf16x8*)(bb + (wn * 4 + 0) * 1024 + lane * 16);
    b1 = *(const bf16x8*)(bb + (wn * 4 + 1) * 1024 + lane * 16);
    if (t + 2 < nt) stA(t + 2, nx2);
    __builtin_amdgcn_s_barrier();
    __builtin_amdgcn_s_setprio(1);
#pragma unroll
    for (int m = 0; m < 8; ++m) {
      acc[m][0] = mfma16x16(a[m], b0, acc[m][0]);
      acc[m][1] = mfma16x16(a[m], b1, acc[m][1]);
    }
    __builtin_amdgcn_s_setprio(0);
    __builtin_amdgcn_s_barrier();

    b0 = *(const bf16x8*)(bb + (wn * 4 + 2) * 1024 + lane * 16);
    b1 = *(const bf16x8*)(bb + (wn * 4 + 3) * 1024 + lane * 16);
    if (t + 2 < nt) stB(t + 2, nx2);
    __builtin_amdgcn_s_barrier();
    __builtin_amdgcn_s_setprio(1);
#pragma unroll
    for (int m = 0; m < 8; ++m) {
      acc[m][2] = mfma16x16(a[m], b0, acc[m][2]);
      acc[m][3] = mfma16x16(a[m], b1, acc[m][3]);
    }
    __builtin_amdgcn_s_setprio(0);
    if (t + 2 < nt) {
      asm volatile("s_waitcnt vmcnt(4)" ::: "memory");
    } else {
      asm volatile("s_waitcnt vmcnt(0)" ::: "memory");
    }
    __builtin_amdgcn_s_barrier();

    cur = (cur == 2) ? 0 : cur + 1;
  }

  // rms-norm epilogue (f32 accum)
  float* ldsf = (float*)lds;
#pragma unroll
  for (int m = 0; m < 8; ++m)
#pragma unroll
    for (int r = 0; r < 4; ++r) {
      float s = acc[m][0][r] * acc[m][0][r] + acc[m][1][r] * acc[m][1][r] +
                acc[m][2][r] * acc[m][2][r] + acc[m][3][r] * acc[m][3][r];
      s += __shfl_xor(s, 1, 64);
      s += __shfl_xor(s, 2, 64);
      s += __shfl_xor(s, 4, 64);
      s += __shfl_xor(s, 8, 64);
      if (l15 == 0) ldsf[(wm * 128 + m * 16 + lhi * 4 + r) * 4 + wn] = s;
    }
  __syncthreads();
  const float osc = (z == 0) ? 0.08838834764831845f : 1.0f;  // fold 1/sqrt(128) into q
  bf16* C = (z == 0) ? Cq : Ck;
#pragma unroll
  for (int m = 0; m < 8; ++m) {
#pragma unroll
    for (int r = 0; r < 4; ++r) {
      int rl = wm * 128 + m * 16 + lhi * 4 + r;
      float tot = ldsf[rl * 4 + (wn & 2)] + ldsf[rl * 4 + (wn & 2) + 1];
      float sc = rsqrtf(tot * (1.0f / 128.0f) + 1.1920929e-07f) * osc;
#pragma unroll
      for (int n = 0; n < 4; ++n) {
        int col = bn + wn * 64 + n * 16 + l15;
        C[(size_t)(bm + rl) * 2048 + col] = (bf16)(acc[m][n][r] * sc);
      }
    }
  }
}

// ---------------- V GEMM (r23-verified, ~46us): r14 engine + V-transpose epilogue ----------------
__global__ __launch_bounds__(512) void gemm_v(const bf16* __restrict__ A, const bf16* __restrict__ B,
                                              bf16* __restrict__ Cv) {
  __shared__ char lds[73728];  // 3 x (A 16KB + B 8KB)
  const int K = 2048, nt = 64;

  int p = blockIdx.x;
  int lid = (p & 7) * 32 + (p >> 3);
  const int bm = (lid >> 4) * 256;
  const int bn = (lid & 15) * 128;

  const int tid = threadIdx.x;
  const int wid = tid >> 6, lane = tid & 63;
  const int l15 = lane & 15, lhi = lane >> 4;
  const int wm = wid >> 1, wn = wid & 1;

  const bf16* aB = A + (size_t)(bm + wid * 16 + l15) * K + lhi * 8;
  const bf16* bB = B + (size_t)(bn + wid * 16 + l15) * K + lhi * 8;

  auto stage = [&](int t, int pb) {
    char* base = lds + pb * 24576;
    const int k0 = t * 32;
    gload16(aB + k0, base + wid * 1024);
    gload16(aB + (size_t)128 * K + k0, base + 8192 + wid * 1024);
    gload16(bB + k0, base + 16384 + wid * 1024);
  };

  const f32x4 fz = {0.f, 0.f, 0.f, 0.f};
  f32x4 acc[4][4];
#pragma unroll
  for (int m = 0; m < 4; ++m)
#pragma unroll
    for (int n = 0; n < 4; ++n) acc[m][n] = fz;

  stage(0, 0);
  stage(1, 1);
  asm volatile("s_waitcnt vmcnt(3)" ::: "memory");
  __builtin_amdgcn_s_barrier();

  for (int t = 0; t < nt; ++t) {
    const char* ab = lds + (t % 3) * 24576;
    if (t + 2 < nt) stage(t + 2, (t + 2) % 3);
    bf16x8 a[4], b[4];
#pragma unroll
    for (int m = 0; m < 4; ++m)
      a[m] = *(const bf16x8*)(ab + (wm * 4 + m) * 1024 + lane * 16);
#pragma unroll
    for (int n = 0; n < 4; ++n)
      b[n] = *(const bf16x8*)(ab + 16384 + (wn * 4 + n) * 1024 + lane * 16);
    __builtin_amdgcn_s_setprio(1);
#pragma unroll
    for (int m = 0; m < 4; ++m)
#pragma unroll
      for (int n = 0; n < 4; ++n) acc[m][n] = mfma16x16(a[m], b[n], acc[m][n]);
    __builtin_amdgcn_s_setprio(0);
    if (t + 2 < nt) {
      asm volatile("s_waitcnt vmcnt(3)" ::: "memory");
    } else {
      asm volatile("s_waitcnt vmcnt(0)" ::: "memory");
    }
    __builtin_amdgcn_s_barrier();
  }

  // V-transpose epilogue: write vtb[b][d][t]
#pragma unroll
  for (int m = 0; m < 4; ++m)
#pragma unroll
    for (int n = 0; n < 4; ++n)
#pragma unroll
      for (int r = 0; r < 4; ++r) {
        int row = bm + wm * 64 + m * 16 + lhi * 4 + r;
        int col = bn + wn * 64 + n * 16 + l15;
        int bb3 = row >> 11, tt = row & 2047;
        Cv[(size_t)bb3 * 2048 * 2048 + (size_t)col * 2048 + tt] = (bf16)acc[m][n][r];
      }
}

// ---------------- output GEMM (r14-verified, ~46us): 256x128, 8 waves, 3-buf vmcnt(3) ----------------
__global__ __launch_bounds__(512) void gemm_out(const bf16* __restrict__ A, const bf16* __restrict__ B,
                                                float* __restrict__ Cf) {
  __shared__ char lds[73728];  // 3 x (A 16KB + B 8KB)
  const int K = 2048, nt = 64;

  int p = blockIdx.x;
  int lid = (p & 7) * 32 + (p >> 3);
  const int bm = (lid >> 4) * 256;
  const int bn = (lid & 15) * 128;

  const int tid = threadIdx.x;
  const int wid = tid >> 6, lane = tid & 63;
  const int l15 = lane & 15, lhi = lane >> 4;
  const int wm = wid >> 1, wn = wid & 1;

  const bf16* aB = A + (size_t)(bm + wid * 16 + l15) * K + lhi * 8;
  const bf16* bB = B + (size_t)(bn + wid * 16 + l15) * K + lhi * 8;

  auto stage = [&](int t, int pb) {
    char* base = lds + pb * 24576;
    const int k0 = t * 32;
    gload16(aB + k0, base + wid * 1024);
    gload16(aB + (size_t)128 * K + k0, base + 8192 + wid * 1024);
    gload16(bB + k0, base + 16384 + wid * 1024);
  };

  const f32x4 fz = {0.f, 0.f, 0.f, 0.f};
  f32x4 acc[4][4];
#pragma unroll
  for (int m = 0; m < 4; ++m)
#pragma unroll
    for (int n = 0; n < 4; ++n) acc[m][n] = fz;

  stage(0, 0);
  stage(1, 1);
  asm volatile("s_waitcnt vmcnt(3)" ::: "memory");
  __builtin_amdgcn_s_barrier();

  for (int t = 0; t < nt; ++t) {
    const char* ab = lds + (t % 3) * 24576;
    if (t + 2 < nt) stage(t + 2, (t + 2) % 3);
    bf16x8 a[4], b[4];
#pragma unroll
    for (int m = 0; m < 4; ++m)
      a[m] = *(const bf16x8*)(ab + (wm * 4 + m) * 1024 + lane * 16);
#pragma unroll
    for (int n = 0; n < 4; ++n)
      b[n] = *(const bf16x8*)(ab + 16384 + (wn * 4 + n) * 1024 + lane * 16);
    __builtin_amdgcn_s_setprio(1);
#pragma unroll
    for (int m = 0; m < 4; ++m)
#pragma unroll
      for (int n = 0; n < 4; ++n) acc[m][n] = mfma16x16(a[m], b[n], acc[m][n]);
    __builtin_amdgcn_s_setprio(0);
    if (t + 2 < nt) {
      asm volatile("s_waitcnt vmcnt(3)" ::: "memory");
    } else {
      asm volatile("s_waitcnt vmcnt(0)" ::: "memory");
    }
    __builtin_amdgcn_s_barrier();
  }

#pragma unroll
  for (int m = 0; m < 4; ++m)
#pragma unroll
    for (int n = 0; n < 4; ++n)
#pragma unroll
      for (int r = 0; r < 4; ++r) {
        int row = bm + wm * 64 + m * 16 + lhi * 4 + r;
        int col = bn + wn * 64 + n * 16 + l15;
        Cf[(size_t)row * 2048 + col] = acc[m][n][r] * 0.2f;
      }
}

// ---------------- dual-stream causal flash attention v10 (r19/r23-verified, ~103us) ----------------
// 8 waves of (stream s=wid>>2, rowgroup rg=wid&3, 16 q-rows). launch_bounds(512,4)
// -> 2 blocks/CU x 8 waves = 4 waves/SIMD. K/VT double-buffer, stage at top of iter,
// ONE barrier/tile, balanced qt pairing, fixed-max softmax (scores bounded by
// sqrt(128) < 12 since q,k are rms-normed and q carries 1/sqrt(128)).
__global__ __launch_bounds__(512, 4) void attn_kernel(const bf16* __restrict__ qb, const bf16* __restrict__ kb,
                                                      const bf16* __restrict__ vtb, bf16* __restrict__ yb,
                                                      const float* __restrict__ lamp) {
  __shared__ char lds[73728];
  const int tid = threadIdx.x;
  const int wid = tid >> 6, lane = tid & 63;
  const int l15 = lane & 15, lhi = lane >> 4;
  char* pl = lds + 65536 + wid * 1024;
  const int s = wid >> 2;   // stream (0: y1, 1: y2)
  const int rg = wid & 3;   // row-group (16 rows)

  const int p = blockIdx.x;
  const int bh = p & 15;
  const int qt = (p < 256) ? (31 - (p >> 4)) : ((p - 256) >> 4);
  const int b = bh >> 3, h = bh & 7;
  const int wr0 = qt * 64 + rg * 16;
  const float lam = lamp[0];

  bf16x8 qf[4];
  {
    const bf16* qrow = qb + (size_t)(b * 2048 + wr0 + l15) * 2048 + h * 256 + s * 128 + lhi * 8;
#pragma unroll
    for (int c = 0; c < 4; ++c) qf[c] = *(const bf16x8*)(qrow + c * 32);
  }

  const f32x4 fz = {0.f, 0.f, 0.f, 0.f};
  f32x4 y[16];
#pragma unroll
  for (int f = 0; f < 16; ++f) y[f] = fz;
  float lsum[4] = {0.f, 0.f, 0.f, 0.f};

  const int nkt = 2 * qt + 2;
  const bf16* kbase = kb + (size_t)(b * 2048) * 2048 + h * 256;
  const bf16* vbase = vtb + (size_t)b * 2048 * 2048 + (size_t)(h * 256) * 2048;

  auto stage = [&](int kt2, int pp) {
    const int t0 = kt2 * 32;
#pragma unroll
    for (int c = 0; c < 2; ++c) {
      int cc = wid * 2 + c;
      int ss = cc >> 3, tg = (cc >> 2) & 1, kc = cc & 3;
      const bf16* sp = kbase + (size_t)(t0 + tg * 16 + l15) * 2048 + ss * 128 + kc * 32 + lhi * 8;
      gload16(sp, lds + pp * 16384 + ss * 8192 + tg * 4096 + kc * 1024);
    }
#pragma unroll
    for (int c = 0; c < 2; ++c) {
      int cc = wid * 2 + c;
      int i = cc >> 2, w4 = cc & 3;
      const bf16* vp = vbase + (size_t)(i * 64 + w4 * 16 + l15) * 2048 + t0 + lhi * 8;
      gload16(vp, lds + 32768 + pp * 16384 + cc * 1024);
    }
  };

  stage(0, 0);
  __syncthreads();

  for (int kt = 0; kt < nkt; ++kt) {
    const int cur = kt & 1;
    const int t0 = kt * 32;
    const bool active = (t0 <= wr0 + 15);
    if (kt + 1 < nkt) stage(kt + 1, cur ^ 1);
    if (active) {
      const char* kc = lds + cur * 16384 + s * 8192;
      const char* vc = lds + 32768 + cur * 16384;
      f32x4 sg[2];
      __builtin_amdgcn_s_setprio(1);
#pragma unroll
      for (int g = 0; g < 2; ++g) {
        f32x4 a = fz;
#pragma unroll
        for (int ks = 0; ks < 4; ++ks)
          a = mfma16x16(qf[ks], *(const bf16x8*)(kc + (g * 4096 + ks * 1024) + lane * 16), a);
        sg[g] = a;
      }
      __builtin_amdgcn_s_setprio(0);
      if (t0 + 31 > wr0) {
#pragma unroll
        for (int g = 0; g < 2; ++g) {
          int col = t0 + g * 16 + l15;
#pragma unroll
          for (int r = 0; r < 4; ++r) {
            int row = wr0 + lhi * 4 + r;
            if (col > row) sg[g][r] = -1e30f;
          }
        }
      }
#pragma unroll
      for (int g = 0; g < 2; ++g)
#pragma unroll
        for (int r = 0; r < 4; ++r) {
          float pv = __expf(sg[g][r] - 12.0f);
          lsum[r] += pv;
          *(bf16*)(pl + ((lhi * 4 + r) * 32 + g * 16 + l15) * 2) = (bf16)pv;
        }
      bf16x8 pa = *(const bf16x8*)(pl + (l15 * 32 + lhi * 8) * 2);
      __builtin_amdgcn_s_setprio(1);
#pragma unroll
      for (int f = 0; f < 16; ++f) {
        bf16x8 vf = *(const bf16x8*)(vc + (f * 64 + lane) * 16);
        y[f] = mfma16x16(pa, vf, y[f]);
      }
      __builtin_amdgcn_s_setprio(0);
    }
    __syncthreads();
  }

  float inv[4];
#pragma unroll
  for (int r = 0; r < 4; ++r) {
    float sv = lsum[r];
    sv += __shfl_xor(sv, 1, 64);
    sv += __shfl_xor(sv, 2, 64);
    sv += __shfl_xor(sv, 4, 64);
    sv += __shfl_xor(sv, 8, 64);
    inv[r] = (s == 0) ? (1.f / sv) : (lam / sv);
  }
  __syncthreads();
  float* yx = (float*)lds;  // [64 rows][256 cols] f32
  if (s == 0) {
#pragma unroll
    for (int f = 0; f < 16; ++f)
#pragma unroll
      for (int r = 0; r < 4; ++r) {
        int rl = rg * 16 + lhi * 4 + r;
        yx[rl * 256 + f * 16 + l15] = y[f][r] * inv[r];
      }
  }
  __syncthreads();
  if (s == 1) {
#pragma unroll
    for (int r = 0; r < 4; ++r) {
      int rl = rg * 16 + lhi * 4 + r;
      bf16* orow = yb + (size_t)(b * 2048 + qt * 64 + rl) * 2048 + h * 256 + l15;
#pragma unroll
      for (int f = 0; f < 16; ++f) {
        float v = yx[rl * 256 + f * 16 + l15] - y[f][r] * inv[r];
        orow[f * 16] = (bf16)v;
      }
    }
  }
}

// ---------------------------------------------------------------------------
extern "C" void kernel_launch(void* const* d_in, const int* in_sizes, int n_in,
                              void* d_out, int out_size, void* d_ws, size_t ws_size,
                              hipStream_t stream) {
  const float* x = (const float*)d_in[0];
  const float* wq = (const float*)d_in[1];
  const float* wk = (const float*)d_in[2];
  const float* wv = (const float*)d_in[3];
  const float* wo = (const float*)d_in[4];
  const float* lq1 = (const float*)d_in[5];
  const float* lk1 = (const float*)d_in[6];
  const float* lq2 = (const float*)d_in[7];
  const float* lk2 = (const float*)d_in[8];
  float* out = (float*)d_out;
  char* ws = (char*)d_ws;

  if (ws_size < 117440516) return;

  bf16* xb = (bf16*)(ws + 0);             // [4096][2048]
  bf16* wqb = (bf16*)(ws + 16777216);     // [2048][2048]
  bf16* wkb = (bf16*)(ws + 25165824);
  bf16* wvb = (bf16*)(ws + 33554432);
  bf16* wob = (bf16*)(ws + 41943040);
  bf16* qbuf = (bf16*)(ws + 50331648);    // [4096][2048]
  bf16* kbuf = (bf16*)(ws + 67108864);    // [4096][2048]
  bf16* vtb = (bf16*)(ws + 83886080);     // [2][2048 d][2048 t]
  bf16* ybuf = (bf16*)(ws + 100663296);   // [4096][2048]
  float* lam = (float*)(ws + 117440512);

  cast_all<<<24576, 256, 0, stream>>>(x, wq, wk, wv, wo, lq1, lk1, lq2, lk2,
                                      xb, wqb, wkb, wvb, wob, lam);

  gemm_qk<<<256, 512, 0, stream>>>(xb, wqb, wkb, qbuf, kbuf);
  gemm_v<<<256, 512, 0, stream>>>(xb, wvb, vtb);

  attn_kernel<<<512, 512, 0, stream>>>(qbuf, kbuf, vtb, ybuf, lam);

  gemm_out<<<256, 512, 0, stream>>>(ybuf, wob, out);
}